// Round 5
// baseline (367.374 us; speedup 1.0000x reference)
//
#include <hip/hip_runtime.h>
#include <hip/hip_bf16.h>
#include <math.h>

#define CC   256
#define HW   (128*128)       // 16384
#define MAT  (CC*CC)         // 65536
#define NBH  2048
#define N0   4096
#define N1   8192
#define N2   16384

typedef __attribute__((ext_vector_type(8))) short bf16x8;
typedef __attribute__((ext_vector_type(4))) float f32x4;

// ---------------------------------------------------------------------------
// k_mats1: A[i][c][d] = M_i[c][d] = sum_o Wf[i,o,c]*Wp[i,o,d]   (bf16 rows 0..255)
//          E[i][o][c2] = sum_c3 Wfuse[o, i*C+c3]*Wo[i,c3,c2]    (fp32 temp)
// ---------------------------------------------------------------------------
__global__ __launch_bounds__(256) void k_mats1(
    const float* __restrict__ Wp, const float* __restrict__ Wf,
    const float* __restrict__ Wo, const float* __restrict__ Wfu,
    __hip_bfloat16* __restrict__ A, float* __restrict__ E)
{
    int idx = blockIdx.x;
    int t = threadIdx.x;
    if (idx < 3*CC) {
        int i = idx >> 8, c = idx & 255;
        const float* wf = Wf + (size_t)i*MAT;
        const float* wp = Wp + (size_t)i*MAT;
        float acc = 0.f;
        for (int o = 0; o < CC; ++o)
            acc += wf[o*CC + c] * wp[o*CC + t];
        A[(size_t)i*512*CC + (size_t)c*CC + t] = __float2bfloat16(acc);
    } else {
        idx -= 3*CC;
        int i = idx >> 8, o = idx & 255;
        const float* wo = Wo + (size_t)i*MAT;
        const float* wfu = Wfu + (size_t)o*(3*CC) + i*CC;
        float acc = 0.f;
        for (int c3 = 0; c3 < CC; ++c3)
            acc += wfu[c3] * wo[c3*CC + t];
        E[(size_t)i*MAT + (size_t)o*CC + t] = acc;
    }
}

// ---------------------------------------------------------------------------
// k_mats2: A[i][256+o][d] = V_i[o][d] = sum_c E_i[o][c]*Wp[i,c,d]   (bf16)
// ---------------------------------------------------------------------------
__global__ __launch_bounds__(256) void k_mats2(
    const float* __restrict__ Wp, const float* __restrict__ E,
    __hip_bfloat16* __restrict__ A)
{
    int idx = blockIdx.x;
    int i = idx >> 8, o = idx & 255;
    int t = threadIdx.x;
    const float* e = E + (size_t)i*MAT + (size_t)o*CC;
    const float* wp = Wp + (size_t)i*MAT;
    float acc = 0.f;
    for (int c = 0; c < CC; ++c)
        acc += e[c] * wp[c*CC + t];
    A[(size_t)i*512*CC + (size_t)(256+o)*CC + t] = __float2bfloat16(acc);
}

// ---------------------------------------------------------------------------
// k_poolA: one (b,c) per block. Reads x[b][c][:][:] = 64 KB fully contiguous.
// Produces binsG[b][c][h][8] (fp32, 4 KB contiguous per block).
// ---------------------------------------------------------------------------
__global__ __launch_bounds__(256) void k_poolA(
    const float* __restrict__ x, float* __restrict__ binsG)
{
    int bc = blockIdx.x;                 // b*256 + c
    int t = threadIdx.x;
    const float4* xp = (const float4*)(x + (size_t)bc*HW);
    __shared__ float bins[128][9];       // [h][bin], pad 9
    int hb = t >> 5;                     // h sub-index within i-group
    int bin = (t & 31) >> 2;
    #pragma unroll 8
    for (int i = 0; i < 16; ++i) {
        float4 v = xp[i*256 + t];
        float s = v.x + v.y + v.z + v.w;
        s += __shfl_xor(s, 1);
        s += __shfl_xor(s, 2);           // sum of 16 w
        if ((t & 3) == 0) bins[i*8 + hb][bin] = s;
    }
    __syncthreads();
    // write 1024 floats coalesced: thread t -> h = t>>1, b0 = (t&1)*4
    int h = t >> 1, b0 = (t & 1) * 4;
    float4 o;
    o.x = bins[h][b0+0]; o.y = bins[h][b0+1];
    o.z = bins[h][b0+2]; o.w = bins[h][b0+3];
    ((float4*)binsG)[(size_t)bc*256 + t] = o;
}

// ---------------------------------------------------------------------------
// k_poolB: one bh per block, 256 thr (thread = c). Reads binsG[b][c][h][8],
// emits Bt (bf16): B0/B1/B2 rows, coalesced writes along c.
// ---------------------------------------------------------------------------
__global__ __launch_bounds__(256) void k_poolB(
    const float* __restrict__ binsG, __hip_bfloat16* __restrict__ Bt)
{
    int bh = blockIdx.x;
    int b = bh >> 7, h = bh & 127;
    int c = threadIdx.x;
    const float* g = binsG + (((size_t)b*256 + c)*128 + h)*8;
    float4 lo = *(const float4*)(g);
    float4 hi = *(const float4*)(g + 4);
    float b8[8] = {lo.x, lo.y, lo.z, lo.w, hi.x, hi.y, hi.z, hi.w};

    __hip_bfloat16* B0 = Bt;
    __hip_bfloat16* B1 = Bt + (size_t)N0*CC;
    __hip_bfloat16* B2 = Bt + (size_t)(N0+N1)*CC;
    B0[((size_t)bh*2 + 0)*CC + c] = __float2bfloat16((b8[0]+b8[1]+b8[2]+b8[3]) * (1.f/64.f));
    B0[((size_t)bh*2 + 1)*CC + c] = __float2bfloat16((b8[4]+b8[5]+b8[6]+b8[7]) * (1.f/64.f));
    #pragma unroll
    for (int j = 0; j < 4; ++j)
        B1[((size_t)bh*4 + j)*CC + c] = __float2bfloat16((b8[2*j]+b8[2*j+1]) * (1.f/32.f));
    #pragma unroll
    for (int j = 0; j < 8; ++j)
        B2[((size_t)bh*8 + j)*CC + c] = __float2bfloat16(b8[j] * (1.f/16.f));
}

// ---------------------------------------------------------------------------
// k_gemm: 1792 blocks x 128 thr. Block tile 128x64, wave tile 64x64.
// Epilogue scatters into Cc[bh][512][16] fp32 (rows 0..255 mp, 256..511 vp).
// ---------------------------------------------------------------------------
__global__ __launch_bounds__(128) void k_gemm(
    const __hip_bfloat16* __restrict__ A,
    const __hip_bfloat16* __restrict__ Bt,
    float* __restrict__ Cc)
{
    int blk = blockIdx.x;
    int br, lb, LP, poff;
    if (blk < 256)      { br = 0; lb = blk;       LP = 1; poff = 0; }
    else if (blk < 768) { br = 1; lb = blk - 256; LP = 2; poff = 2; }
    else                { br = 2; lb = blk - 768; LP = 3; poff = 6; }
    size_t aoff  = (size_t)br*512*CC;
    size_t btoff = (br == 0) ? 0 : (br == 1 ? (size_t)N0*CC : (size_t)(N0+N1)*CC);
    const __hip_bfloat16* Ab = A  + aoff;
    const __hip_bfloat16* Bb = Bt + btoff;

    int rb = lb & 3, cb = lb >> 2;
    int wv = threadIdx.x >> 6, lane = threadIdx.x & 63;
    int row0 = rb*128 + wv*64;
    int col0 = cb*64;
    int lr = lane & 15, lk = (lane >> 4) * 8;

    f32x4 acc[4][4] = {};
    for (int kk = 0; kk < CC; kk += 32) {
        bf16x8 af[4], bfr[4];
        #pragma unroll
        for (int m = 0; m < 4; ++m)
            af[m] = *reinterpret_cast<const bf16x8*>(Ab + (size_t)(row0 + m*16 + lr)*CC + kk + lk);
        #pragma unroll
        for (int n = 0; n < 4; ++n)
            bfr[n] = *reinterpret_cast<const bf16x8*>(Bb + (size_t)(col0 + n*16 + lr)*CC + kk + lk);
        #pragma unroll
        for (int m = 0; m < 4; ++m)
            #pragma unroll
            for (int n = 0; n < 4; ++n)
                acc[m][n] = __builtin_amdgcn_mfma_f32_16x16x32_bf16(af[m], bfr[n], acc[m][n], 0, 0, 0);
    }

    int cr = (lane >> 4) * 4, ccol = lane & 15;
    int pm = (1 << LP) - 1;
    #pragma unroll
    for (int m = 0; m < 4; ++m) {
        #pragma unroll
        for (int n = 0; n < 4; ++n) {
            int colg = col0 + n*16 + ccol;
            int bh = colg >> LP, p = colg & pm;
            float* dst = Cc + (size_t)bh*8192 + poff + p;
            #pragma unroll
            for (int j = 0; j < 4; ++j) {
                int r = row0 + m*16 + cr + j;
                dst[r*16] = acc[m][n][j];
            }
        }
    }
}

// ---------------------------------------------------------------------------
// k_main v5: one bh per block, 256 thr = 4 waves = (w-half ww) x (c-half wc).
// Thread owns ONE w (scalar loads). Per-thread att[14]; single pair-reduce
// via 7.5 KB LDS. mp/vp rows are wave-uniform s_loads. High occupancy.
// ---------------------------------------------------------------------------
template<int L>
__device__ __forceinline__ void softmax_l(float* a) {
    float m = a[0];
    #pragma unroll
    for (int j = 1; j < L; ++j) m = fmaxf(m, a[j]);
    float s = 0.f;
    #pragma unroll
    for (int j = 0; j < L; ++j) { a[j] = __expf(a[j] - m); s += a[j]; }
    float r = 1.f / s;
    #pragma unroll
    for (int j = 0; j < L; ++j) a[j] *= r;
}

__global__ __launch_bounds__(256, 6) void k_main(
    const float* __restrict__ x, const float* __restrict__ Cc,
    float* __restrict__ out)
{
    int bh = blockIdx.x;
    int b = bh >> 7, h = bh & 127;
    int t = threadIdx.x;
    int lane = t & 63;
    int wv = __builtin_amdgcn_readfirstlane(t >> 6);  // 0..3
    int ww = wv >> 1;                                 // w-half
    int wc = wv & 1;                                  // c-parity
    int w = ww*64 + lane;
    const float* Cb = Cc + (size_t)bh * 8192;
    size_t base = ((size_t)b*CC)*HW + (size_t)h*128 + w;
    __shared__ float att_s[128][15];                  // 7680 B

    float att[14];
    #pragma unroll
    for (int p = 0; p < 14; ++p) att[p] = 0.f;

    #pragma unroll 8
    for (int cc = 0; cc < 128; ++cc) {
        int c = cc*2 + wc;
        float xv = x[base + (size_t)c*HW];
        const float* mp = Cb + c*16;                  // wave-uniform s_load
        #pragma unroll
        for (int p = 0; p < 14; ++p) att[p] += xv * mp[p];
    }

    if (wc == 1) {
        #pragma unroll
        for (int p = 0; p < 14; ++p) att_s[w][p] = att[p];
    }
    __syncthreads();
    if (wc == 0) {
        #pragma unroll
        for (int p = 0; p < 14; ++p) att[p] = (att[p] + att_s[w][p]) * 0.0625f;
        softmax_l<2>(att + 0);
        softmax_l<4>(att + 2);
        softmax_l<8>(att + 6);
        #pragma unroll
        for (int p = 0; p < 14; ++p) att_s[w][p] = att[p];
    }
    __syncthreads();
    #pragma unroll
    for (int p = 0; p < 14; ++p) att[p] = att_s[w][p];

    #pragma unroll 8
    for (int oo = 0; oo < 128; ++oo) {
        int o = oo*2 + wc;
        float acc = x[base + (size_t)o*HW];
        const float* vp = Cb + (256 + o)*16;          // wave-uniform s_load
        #pragma unroll
        for (int p = 0; p < 14; ++p) acc += att[p] * vp[p];
        out[base + (size_t)o*HW] = acc;
    }
}

// ---------------------------------------------------------------------------
extern "C" void kernel_launch(void* const* d_in, const int* in_sizes, int n_in,
                              void* d_out, int out_size, void* d_ws, size_t ws_size,
                              hipStream_t stream)
{
    (void)in_sizes; (void)n_in; (void)out_size; (void)ws_size;
    const float* x   = (const float*)d_in[0];
    const float* Wp  = (const float*)d_in[1];
    const float* Wf  = (const float*)d_in[2];
    const float* Wo  = (const float*)d_in[3];
    const float* Wfu = (const float*)d_in[4];
    float* out = (float*)d_out;

    // workspace layout (bytes):
    //   E     fp32 3*MAT     @ 0         =   786432
    //   A     bf16 3*512*256 @ 786432    =   786432
    //   Bt    bf16 28672*256 @ 1572864   = 14680064
    //   Cc    fp32 2048*8192 @ 16252928  = 67108864   (binsG aliases Cc: 16.8 MB,
    //                                                  consumed by poolB before k_gemm writes Cc)
    char* wsb = (char*)d_ws;
    float*          E     = (float*)wsb;
    __hip_bfloat16* A     = (__hip_bfloat16*)(wsb + 786432);
    __hip_bfloat16* Bt    = (__hip_bfloat16*)(wsb + 1572864);
    float*          Cc    = (float*)(wsb + 16252928);
    float*          binsG = Cc;

    k_mats1<<<dim3(6*CC),  dim3(256), 0, stream>>>(Wp, Wf, Wo, Wfu, A, E);
    k_mats2<<<dim3(3*CC),  dim3(256), 0, stream>>>(Wp, E, A);
    k_poolA<<<dim3(4096),  dim3(256), 0, stream>>>(x, binsG);
    k_poolB<<<dim3(NBH),   dim3(256), 0, stream>>>(binsG, Bt);
    k_gemm <<<dim3(1792),  dim3(128), 0, stream>>>(A, Bt, Cc);
    k_main <<<dim3(NBH),   dim3(256), 0, stream>>>(x, Cc, out);
}

// Round 6
// 347.803 us; speedup vs baseline: 1.0563x; 1.0563x over previous
//
#include <hip/hip_runtime.h>
#include <hip/hip_bf16.h>
#include <math.h>

#define CC   256
#define HW   (128*128)       // 16384
#define MAT  (CC*CC)         // 65536
#define NBH  2048
#define N0   4096
#define N1   8192
#define N2   16384

typedef __attribute__((ext_vector_type(8))) short bf16x8;
typedef __attribute__((ext_vector_type(4))) float f32x4;

// ---------------------------------------------------------------------------
// k_mats1: A[i][c][d] = M_i[c][d] = sum_o Wf[i,o,c]*Wp[i,o,d]   (bf16 rows 0..255)
//          E[i][o][c2] = sum_c3 Wfuse[o, i*C+c3]*Wo[i,c3,c2]    (fp32 temp)
// ---------------------------------------------------------------------------
__global__ __launch_bounds__(256) void k_mats1(
    const float* __restrict__ Wp, const float* __restrict__ Wf,
    const float* __restrict__ Wo, const float* __restrict__ Wfu,
    __hip_bfloat16* __restrict__ A, float* __restrict__ E)
{
    int idx = blockIdx.x;
    int t = threadIdx.x;
    if (idx < 3*CC) {
        int i = idx >> 8, c = idx & 255;
        const float* wf = Wf + (size_t)i*MAT;
        const float* wp = Wp + (size_t)i*MAT;
        float acc = 0.f;
        for (int o = 0; o < CC; ++o)
            acc += wf[o*CC + c] * wp[o*CC + t];
        A[(size_t)i*512*CC + (size_t)c*CC + t] = __float2bfloat16(acc);
    } else {
        idx -= 3*CC;
        int i = idx >> 8, o = idx & 255;
        const float* wo = Wo + (size_t)i*MAT;
        const float* wfu = Wfu + (size_t)o*(3*CC) + i*CC;
        float acc = 0.f;
        for (int c3 = 0; c3 < CC; ++c3)
            acc += wfu[c3] * wo[c3*CC + t];
        E[(size_t)i*MAT + (size_t)o*CC + t] = acc;
    }
}

// ---------------------------------------------------------------------------
// k_mats2: A[i][256+o][d] = V_i[o][d] = sum_c E_i[o][c]*Wp[i,c,d]   (bf16)
// ---------------------------------------------------------------------------
__global__ __launch_bounds__(256) void k_mats2(
    const float* __restrict__ Wp, const float* __restrict__ E,
    __hip_bfloat16* __restrict__ A)
{
    int idx = blockIdx.x;
    int i = idx >> 8, o = idx & 255;
    int t = threadIdx.x;
    const float* e = E + (size_t)i*MAT + (size_t)o*CC;
    const float* wp = Wp + (size_t)i*MAT;
    float acc = 0.f;
    for (int c = 0; c < CC; ++c)
        acc += e[c] * wp[c*CC + t];
    A[(size_t)i*512*CC + (size_t)(256+o)*CC + t] = __float2bfloat16(acc);
}

// ---------------------------------------------------------------------------
// k_poolA: one (b,c) per block, 256 thr. Reads 64 KB contiguous via 16 staged
// float4 loads (16 KB in flight per wave). binsG[b][c][h][8] out (4 KB).
// ---------------------------------------------------------------------------
__global__ __launch_bounds__(256) void k_poolA(
    const float* __restrict__ x, float* __restrict__ binsG)
{
    int bc = blockIdx.x;                 // b*256 + c
    int t = threadIdx.x;
    const float4* xp = (const float4*)(x + (size_t)bc*HW) + t;
    __shared__ float bins[128][9];
    float4 v[16];
    #pragma unroll
    for (int i = 0; i < 16; ++i) v[i] = xp[i*256];
    int hb = t >> 5, bin = (t & 31) >> 2;
    #pragma unroll
    for (int i = 0; i < 16; ++i) {
        float s = v[i].x + v[i].y + v[i].z + v[i].w;
        s += __shfl_xor(s, 1);
        s += __shfl_xor(s, 2);           // sum of 16 w
        if ((t & 3) == 0) bins[i*8 + hb][bin] = s;
    }
    __syncthreads();
    int h = t >> 1, b0 = (t & 1) * 4;
    float4 o;
    o.x = bins[h][b0+0]; o.y = bins[h][b0+1];
    o.z = bins[h][b0+2]; o.w = bins[h][b0+3];
    ((float4*)binsG)[(size_t)bc*256 + t] = o;
}

// ---------------------------------------------------------------------------
// k_poolB: one bh per block, 256 thr (thread = c). Reads binsG[b][c][h][8],
// emits Bt (bf16): B0/B1/B2 rows, coalesced writes along c.
// ---------------------------------------------------------------------------
__global__ __launch_bounds__(256) void k_poolB(
    const float* __restrict__ binsG, __hip_bfloat16* __restrict__ Bt)
{
    int bh = blockIdx.x;
    int b = bh >> 7, h = bh & 127;
    int c = threadIdx.x;
    const float* g = binsG + (((size_t)b*256 + c)*128 + h)*8;
    float4 lo = *(const float4*)(g);
    float4 hi = *(const float4*)(g + 4);
    float b8[8] = {lo.x, lo.y, lo.z, lo.w, hi.x, hi.y, hi.z, hi.w};

    __hip_bfloat16* B0 = Bt;
    __hip_bfloat16* B1 = Bt + (size_t)N0*CC;
    __hip_bfloat16* B2 = Bt + (size_t)(N0+N1)*CC;
    B0[((size_t)bh*2 + 0)*CC + c] = __float2bfloat16((b8[0]+b8[1]+b8[2]+b8[3]) * (1.f/64.f));
    B0[((size_t)bh*2 + 1)*CC + c] = __float2bfloat16((b8[4]+b8[5]+b8[6]+b8[7]) * (1.f/64.f));
    #pragma unroll
    for (int j = 0; j < 4; ++j)
        B1[((size_t)bh*4 + j)*CC + c] = __float2bfloat16((b8[2*j]+b8[2*j+1]) * (1.f/32.f));
    #pragma unroll
    for (int j = 0; j < 8; ++j)
        B2[((size_t)bh*8 + j)*CC + c] = __float2bfloat16(b8[j] * (1.f/16.f));
}

// ---------------------------------------------------------------------------
// k_gemm: 1792 blocks x 128 thr. Block tile 128x64, wave tile 64x64.
// Epilogue scatters into Cc[bh][512][16] fp32 (rows 0..255 mp, 256..511 vp).
// ---------------------------------------------------------------------------
__global__ __launch_bounds__(128) void k_gemm(
    const __hip_bfloat16* __restrict__ A,
    const __hip_bfloat16* __restrict__ Bt,
    float* __restrict__ Cc)
{
    int blk = blockIdx.x;
    int br, lb, LP, poff;
    if (blk < 256)      { br = 0; lb = blk;       LP = 1; poff = 0; }
    else if (blk < 768) { br = 1; lb = blk - 256; LP = 2; poff = 2; }
    else                { br = 2; lb = blk - 768; LP = 3; poff = 6; }
    size_t aoff  = (size_t)br*512*CC;
    size_t btoff = (br == 0) ? 0 : (br == 1 ? (size_t)N0*CC : (size_t)(N0+N1)*CC);
    const __hip_bfloat16* Ab = A  + aoff;
    const __hip_bfloat16* Bb = Bt + btoff;

    int rb = lb & 3, cb = lb >> 2;
    int wv = threadIdx.x >> 6, lane = threadIdx.x & 63;
    int row0 = rb*128 + wv*64;
    int col0 = cb*64;
    int lr = lane & 15, lk = (lane >> 4) * 8;

    f32x4 acc[4][4] = {};
    for (int kk = 0; kk < CC; kk += 32) {
        bf16x8 af[4], bfr[4];
        #pragma unroll
        for (int m = 0; m < 4; ++m)
            af[m] = *reinterpret_cast<const bf16x8*>(Ab + (size_t)(row0 + m*16 + lr)*CC + kk + lk);
        #pragma unroll
        for (int n = 0; n < 4; ++n)
            bfr[n] = *reinterpret_cast<const bf16x8*>(Bb + (size_t)(col0 + n*16 + lr)*CC + kk + lk);
        #pragma unroll
        for (int m = 0; m < 4; ++m)
            #pragma unroll
            for (int n = 0; n < 4; ++n)
                acc[m][n] = __builtin_amdgcn_mfma_f32_16x16x32_bf16(af[m], bfr[n], acc[m][n], 0, 0, 0);
    }

    int cr = (lane >> 4) * 4, ccol = lane & 15;
    int pm = (1 << LP) - 1;
    #pragma unroll
    for (int m = 0; m < 4; ++m) {
        #pragma unroll
        for (int n = 0; n < 4; ++n) {
            int colg = col0 + n*16 + ccol;
            int bh = colg >> LP, p = colg & pm;
            float* dst = Cc + (size_t)bh*8192 + poff + p;
            #pragma unroll
            for (int j = 0; j < 4; ++j) {
                int r = row0 + m*16 + cr + j;
                dst[r*16] = acc[m][n][j];
            }
        }
    }
}

// ---------------------------------------------------------------------------
// k_main v6: one bh per block, 4 waves = c (mod 4); lane owns a w-pair
// (float2 over full 128-w row). 16-deep explicit register staging of x loads
// (8 KB in flight/wave). mp/vp rows wave-uniform s_loads; 32-bit voffsets.
// ---------------------------------------------------------------------------
template<int L>
__device__ __forceinline__ void softmax2(float2* a) {
    float mx = a[0].x, my = a[0].y;
    #pragma unroll
    for (int j = 1; j < L; ++j) { mx = fmaxf(mx, a[j].x); my = fmaxf(my, a[j].y); }
    float sx = 0.f, sy = 0.f;
    #pragma unroll
    for (int j = 0; j < L; ++j) {
        a[j].x = __expf(a[j].x - mx); sx += a[j].x;
        a[j].y = __expf(a[j].y - my); sy += a[j].y;
    }
    float rx = 1.f / sx, ry = 1.f / sy;
    #pragma unroll
    for (int j = 0; j < L; ++j) { a[j].x *= rx; a[j].y *= ry; }
}

__global__ __launch_bounds__(256) void k_main(
    const float* __restrict__ x, const float* __restrict__ Cc,
    float* __restrict__ out)
{
    int bh = blockIdx.x;
    int b = bh >> 7, h = bh & 127;
    int t = threadIdx.x;
    int lane = t & 63;
    int wv = __builtin_amdgcn_readfirstlane(t >> 6);   // 0..3
    const float* Cb = Cc + (size_t)bh * 8192;
    // float2 base: x2/o2 pre-offset to (b, h, lane); channel adds c*(HW/2)
    const float2* x2 = (const float2*)x + ((size_t)b*CC)*(HW/2) + h*64 + lane;
    float2*       o2 = (float2*)out     + ((size_t)b*CC)*(HW/2) + h*64 + lane;
    __shared__ float att_sx[2][64][15];                // stride 15: conflict-free
    __shared__ float att_sy[2][64][15];

    float2 att[14];
    #pragma unroll
    for (int p = 0; p < 14; ++p) att[p] = make_float2(0.f, 0.f);

    // ---- pass A: att logits, 4 batches of 16 staged loads ----
    #pragma unroll 1
    for (int ccc = 0; ccc < 4; ++ccc) {
        float2 xv[16];
        #pragma unroll
        for (int j = 0; j < 16; ++j) {
            int c = ccc*64 + j*4 + wv;
            xv[j] = x2[c*(HW/2)];                      // 32-bit voffset form
        }
        #pragma unroll
        for (int j = 0; j < 16; ++j) {
            int c = ccc*64 + j*4 + wv;
            const float* mp = Cb + c*16;               // wave-uniform s_load
            #pragma unroll
            for (int p = 0; p < 14; ++p) {
                att[p].x += xv[j].x * mp[p];
                att[p].y += xv[j].y * mp[p];
            }
        }
    }

    // ---- reduce across the 4 waves (3 barriers, 15 KB LDS) ----
    if (wv >= 2) {
        #pragma unroll
        for (int p = 0; p < 14; ++p) {
            att_sx[wv-2][lane][p] = att[p].x;
            att_sy[wv-2][lane][p] = att[p].y;
        }
    }
    __syncthreads();
    if (wv < 2) {
        #pragma unroll
        for (int p = 0; p < 14; ++p) {
            att[p].x += att_sx[wv][lane][p];
            att[p].y += att_sy[wv][lane][p];
        }
        if (wv == 1) {
            #pragma unroll
            for (int p = 0; p < 14; ++p) {
                att_sx[1][lane][p] = att[p].x;
                att_sy[1][lane][p] = att[p].y;
            }
        }
    }
    __syncthreads();
    if (wv == 0) {
        #pragma unroll
        for (int p = 0; p < 14; ++p) {
            att[p].x = (att[p].x + att_sx[1][lane][p]) * 0.0625f;
            att[p].y = (att[p].y + att_sy[1][lane][p]) * 0.0625f;
        }
        softmax2<2>(att + 0);
        softmax2<4>(att + 2);
        softmax2<8>(att + 6);
        #pragma unroll
        for (int p = 0; p < 14; ++p) {
            att_sx[0][lane][p] = att[p].x;
            att_sy[0][lane][p] = att[p].y;
        }
    }
    __syncthreads();
    #pragma unroll
    for (int p = 0; p < 14; ++p) {
        att[p].x = att_sx[0][lane][p];
        att[p].y = att_sy[0][lane][p];
    }

    // ---- pass B: out = x + att.vp, 4 batches of 16 staged loads ----
    #pragma unroll 1
    for (int ooo = 0; ooo < 4; ++ooo) {
        float2 xv[16];
        #pragma unroll
        for (int j = 0; j < 16; ++j) {
            int o = ooo*64 + j*4 + wv;
            xv[j] = x2[o*(HW/2)];
        }
        #pragma unroll
        for (int j = 0; j < 16; ++j) {
            int o = ooo*64 + j*4 + wv;
            const float* vp = Cb + (256 + o)*16;       // wave-uniform s_load
            float2 acc = xv[j];
            #pragma unroll
            for (int p = 0; p < 14; ++p) {
                acc.x += att[p].x * vp[p];
                acc.y += att[p].y * vp[p];
            }
            o2[o*(HW/2)] = acc;
        }
    }
}

// ---------------------------------------------------------------------------
extern "C" void kernel_launch(void* const* d_in, const int* in_sizes, int n_in,
                              void* d_out, int out_size, void* d_ws, size_t ws_size,
                              hipStream_t stream)
{
    (void)in_sizes; (void)n_in; (void)out_size; (void)ws_size;
    const float* x   = (const float*)d_in[0];
    const float* Wp  = (const float*)d_in[1];
    const float* Wf  = (const float*)d_in[2];
    const float* Wo  = (const float*)d_in[3];
    const float* Wfu = (const float*)d_in[4];
    float* out = (float*)d_out;

    // workspace layout (bytes):
    //   E     fp32 3*MAT     @ 0         =   786432
    //   A     bf16 3*512*256 @ 786432    =   786432
    //   Bt    bf16 28672*256 @ 1572864   = 14680064
    //   Cc    fp32 2048*8192 @ 16252928  = 67108864   (binsG aliases Cc: 16.8 MB,
    //                                                  consumed by poolB before k_gemm writes Cc)
    char* wsb = (char*)d_ws;
    float*          E     = (float*)wsb;
    __hip_bfloat16* A     = (__hip_bfloat16*)(wsb + 786432);
    __hip_bfloat16* Bt    = (__hip_bfloat16*)(wsb + 1572864);
    float*          Cc    = (float*)(wsb + 16252928);
    float*          binsG = Cc;

    k_mats1<<<dim3(6*CC),  dim3(256), 0, stream>>>(Wp, Wf, Wo, Wfu, A, E);
    k_mats2<<<dim3(3*CC),  dim3(256), 0, stream>>>(Wp, E, A);
    k_poolA<<<dim3(4096),  dim3(256), 0, stream>>>(x, binsG);
    k_poolB<<<dim3(NBH),   dim3(256), 0, stream>>>(binsG, Bt);
    k_gemm <<<dim3(1792),  dim3(128), 0, stream>>>(A, Bt, Cc);
    k_main <<<dim3(NBH),   dim3(256), 0, stream>>>(x, Cc, out);
}